// Round 2
// baseline (188.779 us; speedup 1.0000x reference)
//
#include <hip/hip_runtime.h>
#include <cstdint>
#include <cstddef>

// Problem: B=32, S=2048, D=512, H=512
//   sb[b,h]   = state @ W1[:D]                  (fp32, tiny)
//   h         = tanh(tanh(sb + input@W1[D:]))   <-- DOUBLE tanh (reference quirk)
//   logit[b,s]= sum_h h * w2[h]  - 1e30*(1-mask)
//   p         = softmax over S
//   pooled[b,d]= sum_s p[b,s]*input[b,s,d]
// Outputs: pooled (16384 f32) ++ logit (65536 f32)

#define NEG_BIG 1e30f

typedef __attribute__((ext_vector_type(8))) short short8_t;   // 8 x bf16 (4 VGPRs)
typedef __attribute__((ext_vector_type(4))) float f32x4;

__device__ inline unsigned short f2bf(float f){
  union { float f; unsigned int u; } v; v.f = f;
  unsigned int r = v.u + 0x7fffu + ((v.u >> 16) & 1u);   // round-to-nearest-even
  return (unsigned short)(r >> 16);
}

__device__ inline float tanh_fast(float x){
  x = fminf(fmaxf(x, -15.0f), 15.0f);
  float e = __expf(2.0f * x);
  return (e - 1.0f) / (e + 1.0f);
}

// ---------------------------------------------------------------- K0: prep
// blocks 0..31  : sb[b,h] = state[b,:] @ W1[:512,h]          (fp32)
// blocks 32..95 : w1xt[h][k] = bf16(W1[512+k][h])            (64x64 tiled transpose)
__global__ __launch_bounds__(256) void k0_prep(const float* __restrict__ state,
                                               const float* __restrict__ W1,
                                               float* __restrict__ sb,
                                               unsigned short* __restrict__ w1xt){
  const int bid = blockIdx.x, t = threadIdx.x;
  if (bid < 32) {
    __shared__ float st[512];
    st[t]       = state[bid*512 + t];
    st[t + 256] = state[bid*512 + t + 256];
    __syncthreads();
    for (int hh = t; hh < 512; hh += 256){
      float acc = 0.f;
      #pragma unroll 4
      for (int d = 0; d < 512; ++d) acc += st[d] * W1[(size_t)d*512 + hh];
      sb[bid*512 + hh] = acc;
    }
  } else {
    const int q  = bid - 32;           // 0..63
    const int k0 = (q >> 3) * 64;      // k tile origin
    const int h0 = (q & 7) * 64;       // h tile origin
    __shared__ float tile[64][65];
    const int c = t & 63, r0 = t >> 6; // r0 in 0..3
    #pragma unroll
    for (int i = 0; i < 16; ++i){
      int r = r0 + 4*i;
      tile[r][c] = W1[(size_t)(512 + k0 + r)*512 + h0 + c];
    }
    __syncthreads();
    #pragma unroll
    for (int i = 0; i < 16; ++i){
      int r = r0 + 4*i;                // h-row within tile
      w1xt[(size_t)(h0 + r)*512 + k0 + c] = f2bf(tile[c][r]);
    }
  }
}

// ---------------------------------------------------------------- K1: fused GEMM
// grid 2048 = 512 M-tiles x 4 N-tiles. Each block: 128x128 tile, K=512.
// Emits partial logits plog[nt][m] = sum over its 128 h-cols of tanh(tanh(.))*w2.
__global__ __launch_bounds__(256) void k1_gemm(const float* __restrict__ input,
                                               const unsigned short* __restrict__ w1xt,
                                               const float* __restrict__ sb,
                                               const float* __restrict__ w2,
                                               float* __restrict__ plog){
  __shared__ unsigned short lds_a[128][72];   // +8 pad: 144B row stride, even bank spread
  __shared__ unsigned short lds_b[128][72];   // B^T tile: rows = n, cols = k

  // XCD-grouped swizzle: 4 N-tiles of one M-tile land on same XCD back-to-back
  const int orig = blockIdx.x;
  const int xcd  = orig & 7, slot = orig >> 3;
  const int mtile = xcd*64 + (slot >> 2);
  const int nt    = slot & 3;
  const int m0 = mtile * 128;
  const int n0 = nt * 128;
  const int b  = m0 >> 11;               // 2048 rows per batch, BM=128 divides it

  const int t = threadIdx.x;
  const int lane = t & 63, wid = t >> 6;
  const int wr = wid >> 1, wc = wid & 1;  // wave -> 64x64 quadrant
  const int lr = lane & 15, kg = lane >> 4;

  f32x4 acc[4][4];
  #pragma unroll
  for (int mi = 0; mi < 4; ++mi)
    #pragma unroll
    for (int ni = 0; ni < 4; ++ni) acc[mi][ni] = (f32x4){0.f,0.f,0.f,0.f};

  const int ar0 = t >> 4, afo = t & 15;   // A staging: 16 rows x 16 float4/row
  const int br0 = t >> 3, bho = t & 7;    // B staging: 32 rows x 8 uint4/row

  for (int kk = 0; kk < 512; kk += 64){
    // stage A: fp32 -> bf16, 128 x 64
    #pragma unroll
    for (int rr = 0; rr < 8; ++rr){
      const int r = ar0 + rr*16;
      const float4 v = *reinterpret_cast<const float4*>(
          input + (size_t)(m0 + r)*512 + kk + afo*4);
      ushort4 bv; bv.x = f2bf(v.x); bv.y = f2bf(v.y); bv.z = f2bf(v.z); bv.w = f2bf(v.w);
      *reinterpret_cast<ushort4*>(&lds_a[r][afo*4]) = bv;
    }
    // stage B: already bf16, 128 x 64
    #pragma unroll
    for (int rr = 0; rr < 4; ++rr){
      const int r = br0 + rr*32;
      const uint4 v = *reinterpret_cast<const uint4*>(
          w1xt + (size_t)(n0 + r)*512 + kk + bho*8);
      *reinterpret_cast<uint4*>(&lds_b[r][bho*8]) = v;
    }
    __syncthreads();
    #pragma unroll
    for (int ks = 0; ks < 64; ks += 32){
      short8_t af[4], bfr[4];
      #pragma unroll
      for (int mi = 0; mi < 4; ++mi)
        af[mi] = *reinterpret_cast<const short8_t*>(&lds_a[wr*64 + mi*16 + lr][ks + kg*8]);
      #pragma unroll
      for (int ni = 0; ni < 4; ++ni)
        bfr[ni] = *reinterpret_cast<const short8_t*>(&lds_b[wc*64 + ni*16 + lr][ks + kg*8]);
      #pragma unroll
      for (int mi = 0; mi < 4; ++mi)
        #pragma unroll
        for (int ni = 0; ni < 4; ++ni)
          acc[mi][ni] = __builtin_amdgcn_mfma_f32_16x16x32_bf16(af[mi], bfr[ni], acc[mi][ni], 0, 0, 0);
    }
    __syncthreads();
  }

  // epilogue: tanh(tanh(acc + sb)) * w2, reduce over this block's 128 h-cols
  float w2v[4], sbv[4];
  #pragma unroll
  for (int ni = 0; ni < 4; ++ni){
    const int h = n0 + wc*64 + ni*16 + lr;
    w2v[ni] = w2[h];
    sbv[ni] = sb[b*512 + h];
  }
  float* red = reinterpret_cast<float*>(&lds_a[0][0]);   // reuse LDS (post-barrier)
  #pragma unroll
  for (int mi = 0; mi < 4; ++mi){
    #pragma unroll
    for (int j = 0; j < 4; ++j){
      float v = 0.f;
      #pragma unroll
      for (int ni = 0; ni < 4; ++ni)
        v += tanh_fast(tanh_fast(acc[mi][ni][j] + sbv[ni])) * w2v[ni];  // DOUBLE tanh per reference
      v += __shfl_xor(v, 1); v += __shfl_xor(v, 2);
      v += __shfl_xor(v, 4); v += __shfl_xor(v, 8);   // sum across 16 cols
      if (lr == 0){
        const int rloc = wr*64 + mi*16 + kg*4 + j;    // C/D: row=(lane>>4)*4+j
        red[wc*128 + rloc] = v;
      }
    }
  }
  __syncthreads();
  if (t < 128) plog[(size_t)nt*65536 + m0 + t] = red[t] + red[128 + t];
}

// ---------------------------------------------------------------- K2: softmax stats
// one block per batch: sum 4 partials, apply mask, write logit, compute max & Z
__global__ __launch_bounds__(256) void k2_softmax(const float* __restrict__ plog,
                                                  const float* __restrict__ mask,
                                                  float* __restrict__ out_logit,
                                                  float* __restrict__ mz){
  const int b = blockIdx.x, t = threadIdx.x;
  float l[8]; float mx = -3.4e38f;
  #pragma unroll
  for (int i = 0; i < 8; ++i){
    const size_t idx = (size_t)b*2048 + t + i*256;
    float v = plog[idx] + plog[65536 + idx] + plog[2*65536 + idx] + plog[3*65536 + idx];
    v -= NEG_BIG * (1.0f - mask[idx]);
    l[i] = v;
    out_logit[idx] = v;
    mx = fmaxf(mx, v);
  }
  __shared__ float red[8];
  const int wid = t >> 6, lane = t & 63;
  #pragma unroll
  for (int off = 1; off < 64; off <<= 1) mx = fmaxf(mx, __shfl_xor(mx, off));
  if (lane == 0) red[wid] = mx;
  __syncthreads();
  mx = fmaxf(fmaxf(red[0], red[1]), fmaxf(red[2], red[3]));
  float zs = 0.f;
  #pragma unroll
  for (int i = 0; i < 8; ++i) zs += __expf(l[i] - mx);
  #pragma unroll
  for (int off = 1; off < 64; off <<= 1) zs += __shfl_xor(zs, off);
  if (lane == 0) red[4 + wid] = zs;
  __syncthreads();
  if (t == 0){
    mz[b*2]   = mx;
    mz[b*2+1] = red[4] + red[5] + red[6] + red[7];
  }
}

// ---------------------------------------------------------------- K3: pooled partials
// grid 512 = 32 b x 16 s-chunks of 128 rows; each block: 512 d-cols (float2/thread)
__global__ __launch_bounds__(256) void k3_pool(const float* __restrict__ input,
                                               const float* __restrict__ logit,
                                               const float* __restrict__ mz,
                                               float* __restrict__ pool){
  const int b = blockIdx.x >> 4, sc = blockIdx.x & 15;
  const int t = threadIdx.x;
  __shared__ float p[128];
  const float m = mz[b*2], invZ = 1.0f / mz[b*2+1];
  if (t < 128){
    p[t] = __expf(logit[(size_t)b*2048 + sc*128 + t] - m) * invZ;
  }
  __syncthreads();
  float a0 = 0.f, a1 = 0.f;
  const float* base = input + ((size_t)b*2048 + sc*128)*512 + 2*t;
  #pragma unroll 4
  for (int i = 0; i < 128; ++i){
    const float2 v = *reinterpret_cast<const float2*>(base + (size_t)i*512);
    a0 += p[i]*v.x; a1 += p[i]*v.y;
  }
  pool[(size_t)blockIdx.x*512 + 2*t]     = a0;
  pool[(size_t)blockIdx.x*512 + 2*t + 1] = a1;
}

// ---------------------------------------------------------------- K4: reduce partials
__global__ __launch_bounds__(256) void k4_reduce(const float* __restrict__ pool,
                                                 float* __restrict__ out_pooled){
  const int tg = blockIdx.x*256 + threadIdx.x;  // 0..16383
  const int b = tg >> 9, d = tg & 511;
  float s = 0.f;
  #pragma unroll
  for (int c = 0; c < 16; ++c) s += pool[(size_t)(b*16 + c)*512 + d];
  out_pooled[tg] = s;
}

// ---------------------------------------------------------------- launch
extern "C" void kernel_launch(void* const* d_in, const int* in_sizes, int n_in,
                              void* d_out, int out_size, void* d_ws, size_t ws_size,
                              hipStream_t stream){
  const float* input = (const float*)d_in[0];   // 32*2048*512
  const float* state = (const float*)d_in[1];   // 32*512
  const float* mask  = (const float*)d_in[2];   // 32*2048
  const float* W1    = (const float*)d_in[3];   // 1024*512
  const float* w2    = (const float*)d_in[4];   // 512

  float* out_pooled = (float*)d_out;            // 16384
  float* out_logit  = (float*)d_out + 16384;    // 65536

  char* ws = (char*)d_ws;
  float*          sb   = (float*)(ws);                                  //  64 KB
  unsigned short* w1xt = (unsigned short*)(ws + 65536);                 // 512 KB
  float*          plog = (float*)(ws + 65536 + 524288);                 //   1 MB
  float*          mz   = (float*)(ws + 65536 + 524288 + 1048576);       // 256 B
  float*          pool = (float*)(ws + 65536 + 524288 + 1048576 + 256); //   1 MB
  // total ws use: ~2.7 MB

  k0_prep   <<<96,   256, 0, stream>>>(state, W1, sb, w1xt);
  k1_gemm   <<<2048, 256, 0, stream>>>(input, w1xt, sb, w2, plog);
  k2_softmax<<<32,   256, 0, stream>>>(plog, mask, out_logit, mz);
  k3_pool   <<<512,  256, 0, stream>>>(input, out_logit, mz, pool);
  k4_reduce <<<64,   256, 0, stream>>>(pool, out_pooled);
}